// Round 2
// baseline (165.279 us; speedup 1.0000x reference)
//
#include <hip/hip_runtime.h>

#define NB 8
#define CC 32
#define HH 256
#define WW 512
#define DD 64
#define PAD 64
#define RPITCH (WW + PAD)   // 576 words per padded r row in LDS
#define CHUNK 8             // channels per LDS pass
#define NCHUNK (CC / CHUNK) // 4

__global__ __launch_bounds__(512) void cost_volume_kernel(
    const float* __restrict__ L, const float* __restrict__ R, float* __restrict__ O)
{
    // 8 ch x (512 l + 576 r) x 4B = 34 KiB LDS -> 2 blocks/CU (VGPR-capped)
    __shared__ float lA[CHUNK * WW];
    __shared__ float rB[CHUNK * RPITCH];

    const int tid = threadIdx.x;
    const int row = blockIdx.x;          // n*H + h
    const int n = row >> 8;
    const int h = row & 255;

    const size_t inbase = (size_t)n * (CC * HH * WW) + (size_t)h * WW;

    // zero the 64-float left pad of each of the 8 r rows, once.
    // stage loops never touch words [0,64) of a row, so pads stay zero.
    if (tid < CHUNK * 16) {
        const int c = tid >> 4, q = tid & 15;
        *reinterpret_cast<float4*>(&rB[c * RPITCH + q * 4]) =
            make_float4(0.f, 0.f, 0.f, 0.f);
    }

    // thread -> (d-tile, w-chunk)
    const int wave = tid >> 6, lane = tid & 63;
    const int d0 = (wave & 3) * 16;
    const int cw = ((wave >> 2) << 6) + lane;   // [0,128)
    const int w0 = cw * 4;
    const int rbase = PAD + w0 - d0 - 16;       // in [0, 556]

    float acc[16][4];
    #pragma unroll
    for (int dd = 0; dd < 16; ++dd)
        #pragma unroll
        for (int j = 0; j < 4; ++j) acc[dd][j] = 0.f;

    for (int ch = 0; ch < NCHUNK; ++ch) {
        const int c0 = ch * CHUNK;

        __syncthreads();   // compute(ch-1) done before overwriting LDS (and pad visible at ch=0)

        // stage 8 l-rows + 8 r-rows: 1024 float4 each side, 2 per thread
        #pragma unroll
        for (int f = tid; f < CHUNK * WW / 4; f += 512) {
            const int c = f >> 7, q = f & 127;
            const size_t g = inbase + (size_t)(c0 + c) * (HH * WW);
            const float4 lv = reinterpret_cast<const float4*>(L + g)[q];
            const float4 rv = reinterpret_cast<const float4*>(R + g)[q];
            *reinterpret_cast<float4*>(&lA[c * WW + q * 4]) = lv;
            *reinterpret_cast<float4*>(&rB[c * RPITCH + PAD + q * 4]) = rv;
        }

        __syncthreads();   // stage(ch) visible before compute(ch)

        #pragma unroll
        for (int c = 0; c < CHUNK; ++c) {
            const float4 lv = *reinterpret_cast<const float4*>(&lA[c * WW + w0]);
            float rwin[20];
            #pragma unroll
            for (int k = 0; k < 5; ++k) {
                const float4 rv = *reinterpret_cast<const float4*>(&rB[c * RPITCH + rbase + k * 4]);
                rwin[k * 4 + 0] = rv.x; rwin[k * 4 + 1] = rv.y;
                rwin[k * 4 + 2] = rv.z; rwin[k * 4 + 3] = rv.w;
            }
            const float lvv[4] = {lv.x, lv.y, lv.z, lv.w};
            #pragma unroll
            for (int dd = 0; dd < 16; ++dd)
                #pragma unroll
                for (int j = 0; j < 4; ++j)
                    acc[dd][j] = fmaf(lvv[j], rwin[16 + j - dd], acc[dd][j]);
        }
    }

    const float inv = 1.0f / 32.0f;
    const size_t obase = (size_t)n * ((size_t)DD * HH * WW) + (size_t)h * WW + w0;
    #pragma unroll
    for (int dd = 0; dd < 16; ++dd) {
        float4 o;
        o.x = acc[dd][0] * inv; o.y = acc[dd][1] * inv;
        o.z = acc[dd][2] * inv; o.w = acc[dd][3] * inv;
        *reinterpret_cast<float4*>(&O[obase + (size_t)(d0 + dd) * (HH * WW)]) = o;
    }
}

extern "C" void kernel_launch(void* const* d_in, const int* in_sizes, int n_in,
                              void* d_out, int out_size, void* d_ws, size_t ws_size,
                              hipStream_t stream) {
    const float* L = (const float*)d_in[0];
    const float* R = (const float*)d_in[1];
    float* O = (float*)d_out;
    cost_volume_kernel<<<NB * HH, 512, 0, stream>>>(L, R, O);
}